// Round 2
// baseline (96.529 us; speedup 1.0000x reference)
//
#include <hip/hip_runtime.h>

#define NQ 4
#define DIM 16
#define NCOEF 136  // 16*17/2 folded symmetric entries

struct cplx { float r, i; };
__device__ inline cplx cmul(cplx a, cplx b) { return {a.r*b.r - a.i*b.i, a.r*b.i + a.i*b.r}; }
__device__ inline cplx cadd(cplx a, cplx b) { return {a.r + b.r, a.i + b.i}; }

// Build U (16x16 complex) for the shared circuit, then emit folded quadratic-form
// coefficients: coef[u*4 + w] for u-th (j<=k) pair, output w.
__global__ void setup_kernel(const float* __restrict__ wt, float* __restrict__ coef) {
    __shared__ float Ur[DIM][DIM];
    __shared__ float Ui[DIM][DIM];
    int col = threadIdx.x;
    if (col < DIM) {
        float ar[DIM], ai[DIM];
#pragma unroll
        for (int i = 0; i < DIM; ++i) { ar[i] = 0.f; ai[i] = 0.f; }
        ar[col] = 1.f;
        for (int l = 0; l < 2; ++l) {
            for (int q = 0; q < NQ; ++q) {
                float tx = wt[(l * 4 + q) * 3 + 0];
                float ty = wt[(l * 4 + q) * 3 + 1];
                float tz = wt[(l * 4 + q) * 3 + 2];
                float cx = cosf(0.5f * tx), sx = sinf(0.5f * tx);
                float cy = cosf(0.5f * ty), sy = sinf(0.5f * ty);
                float cz = cosf(0.5f * tz), sz = sinf(0.5f * tz);
                cplx Rx[2][2] = {{{cx, 0.f}, {0.f, -sx}}, {{0.f, -sx}, {cx, 0.f}}};
                cplx Ry[2][2] = {{{cy, 0.f}, {-sy, 0.f}}, {{sy, 0.f}, {cy, 0.f}}};
                cplx Rz[2][2] = {{{cz, -sz}, {0.f, 0.f}}, {{0.f, 0.f}, {cz, sz}}};
                cplx T[2][2], G[2][2];
                for (int r = 0; r < 2; ++r)
                    for (int c = 0; c < 2; ++c)
                        T[r][c] = cadd(cmul(Ry[r][0], Rx[0][c]), cmul(Ry[r][1], Rx[1][c]));
                for (int r = 0; r < 2; ++r)
                    for (int c = 0; c < 2; ++c)
                        G[r][c] = cadd(cmul(Rz[r][0], T[0][c]), cmul(Rz[r][1], T[1][c]));
                int pos = 3 - q, mask = 1 << pos;
                for (int idx = 0; idx < DIM; ++idx) {
                    if (idx & mask) continue;
                    int i1 = idx | mask;
                    cplx a0 = {ar[idx], ai[idx]}, a1 = {ar[i1], ai[i1]};
                    cplx n0 = cadd(cmul(G[0][0], a0), cmul(G[0][1], a1));
                    cplx n1 = cadd(cmul(G[1][0], a0), cmul(G[1][1], a1));
                    ar[idx] = n0.r; ai[idx] = n0.i;
                    ar[i1] = n1.r;  ai[i1] = n1.i;
                }
            }
            for (int q = 0; q < NQ; ++q) {
                int cpos = 3 - q, tpos = 3 - ((q + 1) & 3);
                int tmask = 1 << tpos;
                for (int idx = 0; idx < DIM; ++idx) {
                    if (((idx >> cpos) & 1) && !((idx >> tpos) & 1)) {
                        int i1 = idx | tmask;
                        float tr = ar[idx]; ar[idx] = ar[i1]; ar[i1] = tr;
                        float ti = ai[idx]; ai[idx] = ai[i1]; ai[i1] = ti;
                    }
                }
            }
        }
        for (int i = 0; i < DIM; ++i) { Ur[i][col] = ar[i]; Ui[i][col] = ai[i]; }
    }
    __syncthreads();
    for (int id = threadIdx.x; id < 4 * NCOEF; id += blockDim.x) {
        int u = id >> 2, wo = id & 3;
        int j = 0, rem = u;
        while (rem >= DIM - j) { rem -= DIM - j; ++j; }
        int k = j + rem;
        float acc = 0.f;
        for (int idx = 0; idx < DIM; ++idx) {
            float sgn = ((idx >> (3 - wo)) & 1) ? -1.f : 1.f;
            acc += sgn * (Ur[idx][j] * Ur[idx][k] + Ui[idx][j] * Ui[idx][k]);
        }
        coef[id] = (j == k) ? acc : 2.f * acc;
    }
}

__device__ inline void build_state(float4 xv, float* s) {
    float c0, s0, c1, s1, c2, s2, c3, s3;
    __sincosf(0.5f * xv.x, &s0, &c0);
    __sincosf(0.5f * xv.y, &s1, &c1);
    __sincosf(0.5f * xv.z, &s2, &c2);
    __sincosf(0.5f * xv.w, &s3, &c3);
    float p01[4] = {c0 * c1, c0 * s1, s0 * c1, s0 * s1};
    float p23[4] = {c2 * c3, c2 * s3, s2 * c3, s2 * s3};
#pragma unroll
    for (int a = 0; a < 4; ++a)
#pragma unroll
        for (int b = 0; b < 4; ++b)
            s[a * 4 + b] = p01[a] * p23[b];
}

// coef staged in LDS: per-iteration ds_read_b128 at compile-time offset,
// broadcast (same address all lanes) -> conflict-free, no VGPR hoard.
__global__ __launch_bounds__(256) void qsim_kernel(const float4* __restrict__ x,
                                                   const float4* __restrict__ coef,
                                                   float4* __restrict__ out, int nthreads) {
    __shared__ float4 lcoef[NCOEF];
    for (int i = threadIdx.x; i < NCOEF; i += blockDim.x) lcoef[i] = coef[i];
    __syncthreads();

    int tid = blockIdx.x * blockDim.x + threadIdx.x;
    if (tid >= nthreads) return;
    float4 xa = x[2 * tid + 0];
    float4 xb = x[2 * tid + 1];
    float sA[DIM], sB[DIM];
    build_state(xa, sA);
    build_state(xb, sB);
    float a0 = 0.f, a1 = 0.f, a2 = 0.f, a3 = 0.f;
    float b0 = 0.f, b1 = 0.f, b2 = 0.f, b3 = 0.f;
    int t = 0;
#pragma unroll
    for (int j = 0; j < DIM; ++j) {
#pragma unroll
        for (int k = j; k < DIM; ++k, ++t) {
            float4 c = lcoef[t];  // ds_read_b128, immediate offset, broadcast
            float pa = sA[j] * sA[k];
            float pb = sB[j] * sB[k];
            a0 = fmaf(c.x, pa, a0);
            a1 = fmaf(c.y, pa, a1);
            a2 = fmaf(c.z, pa, a2);
            a3 = fmaf(c.w, pa, a3);
            b0 = fmaf(c.x, pb, b0);
            b1 = fmaf(c.y, pb, b1);
            b2 = fmaf(c.z, pb, b2);
            b3 = fmaf(c.w, pb, b3);
        }
    }
    out[2 * tid + 0] = make_float4(a0, a1, a2, a3);
    out[2 * tid + 1] = make_float4(b0, b1, b2, b3);
}

extern "C" void kernel_launch(void* const* d_in, const int* in_sizes, int n_in,
                              void* d_out, int out_size, void* d_ws, size_t ws_size,
                              hipStream_t stream) {
    const float* x = (const float*)d_in[0];
    const float* wt = (const float*)d_in[1];
    float* out = (float*)d_out;
    float* coef = (float*)d_ws;  // 544 floats = 2176 B

    setup_kernel<<<1, 256, 0, stream>>>(wt, coef);

    int B = in_sizes[0] / NQ;      // 2^20 samples
    int nthreads = B / 2;          // 2 samples per thread
    int blocks = (nthreads + 255) / 256;
    qsim_kernel<<<blocks, 256, 0, stream>>>((const float4*)x, (const float4*)coef,
                                            (float4*)out, nthreads);
}

// Round 3
// 91.131 us; speedup vs baseline: 1.0592x; 1.0592x over previous
//
#include <hip/hip_runtime.h>

#define NQ 4
#define DIM 16

struct cplx { float r, i; };
__device__ inline cplx cmul(cplx a, cplx b) { return {a.r*b.r - a.i*b.i, a.r*b.i + a.i*b.r}; }
__device__ inline cplx cadd(cplx a, cplx b) { return {a.r + b.r, a.i + b.i}; }

// Build U (16x16 complex) for the shared circuit, form A_w = Re(U^T Z_w U*)
// (real symmetric), then transform to the trig basis:
//   out_w = sum_{e in {1,cos,sin}^4} K_w[e] * prod_q f_{e_q}(x_q)
// using c^2=(1+cos)/2, s^2=(1-cos)/2, cs=sin/2 per qubit (half-angle -> full-angle).
// K_w[e] = (1/16) * sum_b A_w[b][b^m] * parity(b & d1), where m has bits of e_q==2
// (sin -> off-diagonal), d1 has bits of e_q==1 (cos -> diagonal sign).
// Layout: coef[u*4 + w], u = (e0*3+e1)*9 + (e2*3+e3)  -> float4 per u for qsim.
__global__ void setup_kernel(const float* __restrict__ wt, float* __restrict__ coef) {
    __shared__ float Ur[DIM][DIM];
    __shared__ float Ui[DIM][DIM];
    __shared__ float A[4][DIM][DIM];
    int col = threadIdx.x;
    if (col < DIM) {
        float ar[DIM], ai[DIM];
#pragma unroll
        for (int i = 0; i < DIM; ++i) { ar[i] = 0.f; ai[i] = 0.f; }
        ar[col] = 1.f;
        for (int l = 0; l < 2; ++l) {
            for (int q = 0; q < NQ; ++q) {
                float tx = wt[(l * 4 + q) * 3 + 0];
                float ty = wt[(l * 4 + q) * 3 + 1];
                float tz = wt[(l * 4 + q) * 3 + 2];
                float cx = cosf(0.5f * tx), sx = sinf(0.5f * tx);
                float cy = cosf(0.5f * ty), sy = sinf(0.5f * ty);
                float cz = cosf(0.5f * tz), sz = sinf(0.5f * tz);
                cplx Rx[2][2] = {{{cx, 0.f}, {0.f, -sx}}, {{0.f, -sx}, {cx, 0.f}}};
                cplx Ry[2][2] = {{{cy, 0.f}, {-sy, 0.f}}, {{sy, 0.f}, {cy, 0.f}}};
                cplx Rz[2][2] = {{{cz, -sz}, {0.f, 0.f}}, {{0.f, 0.f}, {cz, sz}}};
                cplx T[2][2], G[2][2];
                for (int r = 0; r < 2; ++r)
                    for (int c = 0; c < 2; ++c)
                        T[r][c] = cadd(cmul(Ry[r][0], Rx[0][c]), cmul(Ry[r][1], Rx[1][c]));
                for (int r = 0; r < 2; ++r)
                    for (int c = 0; c < 2; ++c)
                        G[r][c] = cadd(cmul(Rz[r][0], T[0][c]), cmul(Rz[r][1], T[1][c]));
                int pos = 3 - q, mask = 1 << pos;
                for (int idx = 0; idx < DIM; ++idx) {
                    if (idx & mask) continue;
                    int i1 = idx | mask;
                    cplx a0 = {ar[idx], ai[idx]}, a1 = {ar[i1], ai[i1]};
                    cplx n0 = cadd(cmul(G[0][0], a0), cmul(G[0][1], a1));
                    cplx n1 = cadd(cmul(G[1][0], a0), cmul(G[1][1], a1));
                    ar[idx] = n0.r; ai[idx] = n0.i;
                    ar[i1] = n1.r;  ai[i1] = n1.i;
                }
            }
            for (int q = 0; q < NQ; ++q) {
                int cpos = 3 - q, tpos = 3 - ((q + 1) & 3);
                int tmask = 1 << tpos;
                for (int idx = 0; idx < DIM; ++idx) {
                    if (((idx >> cpos) & 1) && !((idx >> tpos) & 1)) {
                        int i1 = idx | tmask;
                        float tr = ar[idx]; ar[idx] = ar[i1]; ar[i1] = tr;
                        float ti = ai[idx]; ai[idx] = ai[i1]; ai[i1] = ti;
                    }
                }
            }
        }
        for (int i = 0; i < DIM; ++i) { Ur[i][col] = ar[i]; Ui[i][col] = ai[i]; }
    }
    __syncthreads();
    // A_w[j][k] = sum_idx sign_w(idx) * (Ur[idx][j]Ur[idx][k] + Ui[idx][j]Ui[idx][k])
    for (int id = threadIdx.x; id < 4 * DIM * DIM; id += blockDim.x) {
        int w = id >> 8, j = (id >> 4) & 15, k = id & 15;
        float acc = 0.f;
        for (int idx = 0; idx < DIM; ++idx) {
            float sgn = ((idx >> (3 - w)) & 1) ? -1.f : 1.f;
            acc += sgn * (Ur[idx][j] * Ur[idx][k] + Ui[idx][j] * Ui[idx][k]);
        }
        A[w][j][k] = acc;
    }
    __syncthreads();
    // K transform: 81 trig-basis entries x 4 outputs.
    for (int id = threadIdx.x; id < 4 * 81; id += blockDim.x) {
        int w = id & 3, u = id >> 2;
        int e0 = u / 27, e1 = (u / 9) % 3, e2 = (u / 3) % 3, e3 = u % 3;
        int m  = ((e0 == 2) ? 8 : 0) | ((e1 == 2) ? 4 : 0) | ((e2 == 2) ? 2 : 0) | ((e3 == 2) ? 1 : 0);
        int d1 = ((e0 == 1) ? 8 : 0) | ((e1 == 1) ? 4 : 0) | ((e2 == 1) ? 2 : 0) | ((e3 == 1) ? 1 : 0);
        float acc = 0.f;
        for (int b = 0; b < DIM; ++b) {
            float sgn = (__popc(b & d1) & 1) ? -1.f : 1.f;
            acc += sgn * A[w][b][b ^ m];
        }
        coef[u * 4 + w] = 0.0625f * acc;
    }
}

// t[9] = (1, cos v, sin v, cos u, cu*cv, cu*sv, sin u, su*cv, su*sv)
__device__ inline void build9(float u, float v, float* t) {
    float su, cu, sv, cv;
    __sincosf(u, &su, &cu);
    __sincosf(v, &sv, &cv);
    t[0] = 1.f;      t[1] = cv;      t[2] = sv;
    t[3] = cu;       t[4] = cu * cv; t[5] = cu * sv;
    t[6] = su;       t[7] = su * cv; t[8] = su * sv;
}

__global__ __launch_bounds__(256) void qsim_kernel(const float4* __restrict__ x,
                                                   const float4* __restrict__ coef,
                                                   float4* __restrict__ out, int half) {
    __shared__ float4 lk[81];
    if (threadIdx.x < 81) lk[threadIdx.x] = coef[threadIdx.x];
    __syncthreads();

    int tid = blockIdx.x * blockDim.x + threadIdx.x;
    if (tid >= half) return;
    float4 xa = x[tid];          // coalesced: lane i -> 16B at 16*i
    float4 xb = x[tid + half];
    float ta[9], ua[9], tb[9], ub[9];
    build9(xa.x, xa.y, ta);  build9(xa.z, xa.w, ua);
    build9(xb.x, xb.y, tb);  build9(xb.z, xb.w, ub);

    float4 accA = make_float4(0.f, 0.f, 0.f, 0.f);
    float4 accB = make_float4(0.f, 0.f, 0.f, 0.f);
#pragma unroll
    for (int i = 0; i < 9; ++i) {
#pragma unroll
        for (int j = 0; j < 9; ++j) {
            float4 c = lk[i * 9 + j];   // ds_read_b128, imm offset, broadcast
            float pa = ta[i] * ua[j];
            float pb = tb[i] * ub[j];
            accA.x = fmaf(c.x, pa, accA.x);
            accA.y = fmaf(c.y, pa, accA.y);
            accA.z = fmaf(c.z, pa, accA.z);
            accA.w = fmaf(c.w, pa, accA.w);
            accB.x = fmaf(c.x, pb, accB.x);
            accB.y = fmaf(c.y, pb, accB.y);
            accB.z = fmaf(c.z, pb, accB.z);
            accB.w = fmaf(c.w, pb, accB.w);
        }
    }
    out[tid] = accA;
    out[tid + half] = accB;
}

extern "C" void kernel_launch(void* const* d_in, const int* in_sizes, int n_in,
                              void* d_out, int out_size, void* d_ws, size_t ws_size,
                              hipStream_t stream) {
    const float* x = (const float*)d_in[0];
    const float* wt = (const float*)d_in[1];
    float* out = (float*)d_out;
    float* coef = (float*)d_ws;  // 324 floats

    setup_kernel<<<1, 256, 0, stream>>>(wt, coef);

    int B = in_sizes[0] / NQ;   // 2^20 samples
    int half = B / 2;           // 2 samples per thread
    int blocks = (half + 255) / 256;
    qsim_kernel<<<blocks, 256, 0, stream>>>((const float4*)x, (const float4*)coef,
                                            (float4*)out, half);
}

// Round 4
// 84.179 us; speedup vs baseline: 1.1467x; 1.0826x over previous
//
#include <hip/hip_runtime.h>

#define NQ 4
#define DIM 16

struct cplx { float r, i; };
__device__ inline cplx cmul(cplx a, cplx b) { return {a.r*b.r - a.i*b.i, a.r*b.i + a.i*b.r}; }
__device__ inline cplx cadd(cplx a, cplx b) { return {a.r + b.r, a.i + b.i}; }

// Build U (16x16 complex) for the shared circuit, form A_w = sum_idx sign_w *
// (Ur Ur + Ui Ui) (real symmetric), then transform to the full-angle trig basis:
//   out_w = sum_{e in {1,cos,sin}^4} K_w[e] * prod_q f_{e_q}(x_q)
// via c^2=(1+cos)/2, s^2=(1-cos)/2, cs=sin/2.
// K_w[e] = (1/16) sum_b A_w[b][b^m] * parity(b & d1); m = sin-bits, d1 = cos-bits.
// Layout: coef[u*4+w], u=(e0*3+e1)*9+(e2*3+e3) -> float4 per u.
__global__ void setup_kernel(const float* __restrict__ wt, float* __restrict__ coef) {
    __shared__ float Ur[DIM][DIM];
    __shared__ float Ui[DIM][DIM];
    __shared__ float A[4][DIM][DIM];
    int col = threadIdx.x;
    if (col < DIM) {
        float ar[DIM], ai[DIM];
#pragma unroll
        for (int i = 0; i < DIM; ++i) { ar[i] = 0.f; ai[i] = 0.f; }
        ar[col] = 1.f;
        for (int l = 0; l < 2; ++l) {
            for (int q = 0; q < NQ; ++q) {
                float tx = wt[(l * 4 + q) * 3 + 0];
                float ty = wt[(l * 4 + q) * 3 + 1];
                float tz = wt[(l * 4 + q) * 3 + 2];
                float cx, sx, cy, sy, cz, sz;
                __sincosf(0.5f * tx, &sx, &cx);
                __sincosf(0.5f * ty, &sy, &cy);
                __sincosf(0.5f * tz, &sz, &cz);
                cplx Rx[2][2] = {{{cx, 0.f}, {0.f, -sx}}, {{0.f, -sx}, {cx, 0.f}}};
                cplx Ry[2][2] = {{{cy, 0.f}, {-sy, 0.f}}, {{sy, 0.f}, {cy, 0.f}}};
                cplx Rz[2][2] = {{{cz, -sz}, {0.f, 0.f}}, {{0.f, 0.f}, {cz, sz}}};
                cplx T[2][2], G[2][2];
#pragma unroll
                for (int r = 0; r < 2; ++r)
#pragma unroll
                    for (int c = 0; c < 2; ++c)
                        T[r][c] = cadd(cmul(Ry[r][0], Rx[0][c]), cmul(Ry[r][1], Rx[1][c]));
#pragma unroll
                for (int r = 0; r < 2; ++r)
#pragma unroll
                    for (int c = 0; c < 2; ++c)
                        G[r][c] = cadd(cmul(Rz[r][0], T[0][c]), cmul(Rz[r][1], T[1][c]));
                int pos = 3 - q, mask = 1 << pos;
#pragma unroll
                for (int idx = 0; idx < DIM; ++idx) {
                    if (idx & mask) continue;
                    int i1 = idx | mask;
                    cplx a0 = {ar[idx], ai[idx]}, a1 = {ar[i1], ai[i1]};
                    cplx n0 = cadd(cmul(G[0][0], a0), cmul(G[0][1], a1));
                    cplx n1 = cadd(cmul(G[1][0], a0), cmul(G[1][1], a1));
                    ar[idx] = n0.r; ai[idx] = n0.i;
                    ar[i1] = n1.r;  ai[i1] = n1.i;
                }
            }
            for (int q = 0; q < NQ; ++q) {
                int cpos = 3 - q, tpos = 3 - ((q + 1) & 3);
                int tmask = 1 << tpos;
#pragma unroll
                for (int idx = 0; idx < DIM; ++idx) {
                    if (((idx >> cpos) & 1) && !((idx >> tpos) & 1)) {
                        int i1 = idx | tmask;
                        float tr = ar[idx]; ar[idx] = ar[i1]; ar[i1] = tr;
                        float ti = ai[idx]; ai[idx] = ai[i1]; ai[i1] = ti;
                    }
                }
            }
        }
        for (int i = 0; i < DIM; ++i) { Ur[i][col] = ar[i]; Ui[i][col] = ai[i]; }
    }
    __syncthreads();
    // One (j,k) pair per thread; accumulate all 4 outputs sharing the product.
    // LDS reads: Ur[idx][j]/Ur[idx][k] -> 16 distinct addrs x 4-way broadcast,
    // conflict-free. 64 reads/thread (was 256).
    {
        int j = threadIdx.x >> 4, k = threadIdx.x & 15;
        float a0 = 0.f, a1 = 0.f, a2 = 0.f, a3 = 0.f;
#pragma unroll
        for (int idx = 0; idx < DIM; ++idx) {
            float rr = Ur[idx][j] * Ur[idx][k] + Ui[idx][j] * Ui[idx][k];
            a0 += (idx & 8) ? -rr : rr;
            a1 += (idx & 4) ? -rr : rr;
            a2 += (idx & 2) ? -rr : rr;
            a3 += (idx & 1) ? -rr : rr;
        }
        A[0][j][k] = a0; A[1][j][k] = a1; A[2][j][k] = a2; A[3][j][k] = a3;
    }
    __syncthreads();
    // K transform: 81 trig-basis entries x 4 outputs = 324 values.
    for (int id = threadIdx.x; id < 4 * 81; id += blockDim.x) {
        int w = id & 3, u = id >> 2;
        int e0 = u / 27, e1 = (u / 9) % 3, e2 = (u / 3) % 3, e3 = u % 3;
        int m  = ((e0 == 2) ? 8 : 0) | ((e1 == 2) ? 4 : 0) | ((e2 == 2) ? 2 : 0) | ((e3 == 2) ? 1 : 0);
        int d1 = ((e0 == 1) ? 8 : 0) | ((e1 == 1) ? 4 : 0) | ((e2 == 1) ? 2 : 0) | ((e3 == 1) ? 1 : 0);
        float acc = 0.f;
#pragma unroll
        for (int b = 0; b < DIM; ++b) {
            float sgn = (__popc(b & d1) & 1) ? -1.f : 1.f;
            acc += sgn * A[w][b][b ^ m];
        }
        coef[u * 4 + w] = 0.0625f * acc;
    }
}

// t[9] = (1, cos v, sin v, cos u, cu*cv, cu*sv, sin u, su*cv, su*sv)
__device__ inline void build9(float u, float v, float* t) {
    float su, cu, sv, cv;
    __sincosf(u, &su, &cu);
    __sincosf(v, &sv, &cv);
    t[0] = 1.f;      t[1] = cv;      t[2] = sv;
    t[3] = cu;       t[4] = cu * cv; t[5] = cu * sv;
    t[6] = su;       t[7] = su * cv; t[8] = su * sv;
}

__global__ __launch_bounds__(256) void qsim_kernel(const float4* __restrict__ x,
                                                   const float4* __restrict__ coef,
                                                   float4* __restrict__ out, int half) {
    __shared__ float4 lk[81];
    if (threadIdx.x < 81) lk[threadIdx.x] = coef[threadIdx.x];
    __syncthreads();

    int tid = blockIdx.x * blockDim.x + threadIdx.x;
    if (tid >= half) return;
    float4 xa = x[tid];          // coalesced: lane i -> 16B at 16*i
    float4 xb = x[tid + half];
    float ta[9], ua[9], tb[9], ub[9];
    build9(xa.x, xa.y, ta);  build9(xa.z, xa.w, ua);
    build9(xb.x, xb.y, tb);  build9(xb.z, xb.w, ub);

    float4 accA = make_float4(0.f, 0.f, 0.f, 0.f);
    float4 accB = make_float4(0.f, 0.f, 0.f, 0.f);
#pragma unroll
    for (int i = 0; i < 9; ++i) {
#pragma unroll
        for (int j = 0; j < 9; ++j) {
            float4 c = lk[i * 9 + j];   // ds_read_b128, imm offset, broadcast
            float pa = ta[i] * ua[j];
            float pb = tb[i] * ub[j];
            accA.x = fmaf(c.x, pa, accA.x);
            accA.y = fmaf(c.y, pa, accA.y);
            accA.z = fmaf(c.z, pa, accA.z);
            accA.w = fmaf(c.w, pa, accA.w);
            accB.x = fmaf(c.x, pb, accB.x);
            accB.y = fmaf(c.y, pb, accB.y);
            accB.z = fmaf(c.z, pb, accB.z);
            accB.w = fmaf(c.w, pb, accB.w);
        }
    }
    out[tid] = accA;
    out[tid + half] = accB;
}

extern "C" void kernel_launch(void* const* d_in, const int* in_sizes, int n_in,
                              void* d_out, int out_size, void* d_ws, size_t ws_size,
                              hipStream_t stream) {
    const float* x = (const float*)d_in[0];
    const float* wt = (const float*)d_in[1];
    float* out = (float*)d_out;
    float* coef = (float*)d_ws;  // 324 floats

    setup_kernel<<<1, 256, 0, stream>>>(wt, coef);

    int B = in_sizes[0] / NQ;   // 2^20 samples
    int half = B / 2;           // 2 samples per thread
    int blocks = (half + 255) / 256;
    qsim_kernel<<<blocks, 256, 0, stream>>>((const float4*)x, (const float4*)coef,
                                            (float4*)out, half);
}

// Round 6
// 83.922 us; speedup vs baseline: 1.1502x; 1.0031x over previous
//
#include <hip/hip_runtime.h>

#define NQ 4
#define DIM 16

struct cplx { float r, i; };
__device__ inline cplx cmul(cplx a, cplx b) { return {a.r*b.r - a.i*b.i, a.r*b.i + a.i*b.r}; }
__device__ inline cplx cadd(cplx a, cplx b) { return {a.r + b.r, a.i + b.i}; }

// t[9] = (1, cos v, sin v, cos u, cu*cv, cu*sv, sin u, su*cv, su*sv)
__device__ inline void build9(float u, float v, float* t) {
    float su, cu, sv, cv;
    __sincosf(u, &su, &cu);
    __sincosf(v, &sv, &cv);
    t[0] = 1.f;      t[1] = cv;      t[2] = sv;
    t[3] = cu;       t[4] = cu * cv; t[5] = cu * sv;
    t[6] = su;       t[7] = su * cv; t[8] = su * sv;
}

// Fully fused: every block redundantly builds the 324 trig-basis coefficients in
// its own LDS, then runs the per-sample contraction. Removes the setup dispatch,
// its launch gap, and the coef global round-trip.
//
//   out_w = sum_{e in {1,cos,sin}^4} K_w[e] * prod_q f_{e_q}(x_q)
//   K_w[e] = (1/16) sum_b A_w[b][b^m] * parity(b & d1)   (m=sin-bits, d1=cos-bits)
//   A_w[j][k] = sum_idx sign_w(idx) * (Ur[idx][j]Ur[idx][k] + Ui[idx][j]Ui[idx][k])
__global__ __launch_bounds__(256) void qsim_kernel(const float4* __restrict__ x,
                                                   const float* __restrict__ wt,
                                                   float4* __restrict__ out, int half) {
    __shared__ float Ur[DIM][DIM];
    __shared__ float Ui[DIM][DIM];
    __shared__ float A[4][DIM][DIM];
    __shared__ float4 lk[81];

    int tid = blockIdx.x * blockDim.x + threadIdx.x;
    bool valid = tid < half;
    // Issue input loads first — HBM latency hides behind the setup phases.
    float4 xa = valid ? x[tid] : make_float4(0.f, 0.f, 0.f, 0.f);
    float4 xb = valid ? x[tid + half] : make_float4(0.f, 0.f, 0.f, 0.f);

    // ---- Phase 1: evolve basis columns through the shared circuit (16 lanes) ----
    int col = threadIdx.x;
    if (col < DIM) {
        float ar[DIM], ai[DIM];
#pragma unroll
        for (int i = 0; i < DIM; ++i) { ar[i] = 0.f; ai[i] = 0.f; }
        ar[col] = 1.f;
        for (int l = 0; l < 2; ++l) {
            for (int q = 0; q < NQ; ++q) {
                float tx = wt[(l * 4 + q) * 3 + 0];
                float ty = wt[(l * 4 + q) * 3 + 1];
                float tz = wt[(l * 4 + q) * 3 + 2];
                float cx, sx, cy, sy, cz, sz;
                __sincosf(0.5f * tx, &sx, &cx);
                __sincosf(0.5f * ty, &sy, &cy);
                __sincosf(0.5f * tz, &sz, &cz);
                cplx Rx[2][2] = {{{cx, 0.f}, {0.f, -sx}}, {{0.f, -sx}, {cx, 0.f}}};
                cplx Ry[2][2] = {{{cy, 0.f}, {-sy, 0.f}}, {{sy, 0.f}, {cy, 0.f}}};
                cplx Rz[2][2] = {{{cz, -sz}, {0.f, 0.f}}, {{0.f, 0.f}, {cz, sz}}};
                cplx T[2][2], G[2][2];
#pragma unroll
                for (int r = 0; r < 2; ++r)
#pragma unroll
                    for (int c = 0; c < 2; ++c)
                        T[r][c] = cadd(cmul(Ry[r][0], Rx[0][c]), cmul(Ry[r][1], Rx[1][c]));
#pragma unroll
                for (int r = 0; r < 2; ++r)
#pragma unroll
                    for (int c = 0; c < 2; ++c)
                        G[r][c] = cadd(cmul(Rz[r][0], T[0][c]), cmul(Rz[r][1], T[1][c]));
                int pos = 3 - q, mask = 1 << pos;
#pragma unroll
                for (int idx = 0; idx < DIM; ++idx) {
                    if (idx & mask) continue;
                    int i1 = idx | mask;
                    cplx a0 = {ar[idx], ai[idx]}, a1 = {ar[i1], ai[i1]};
                    cplx n0 = cadd(cmul(G[0][0], a0), cmul(G[0][1], a1));
                    cplx n1 = cadd(cmul(G[1][0], a0), cmul(G[1][1], a1));
                    ar[idx] = n0.r; ai[idx] = n0.i;
                    ar[i1] = n1.r;  ai[i1] = n1.i;
                }
            }
            for (int q = 0; q < NQ; ++q) {
                int cpos = 3 - q, tpos = 3 - ((q + 1) & 3);
                int tmask = 1 << tpos;
#pragma unroll
                for (int idx = 0; idx < DIM; ++idx) {
                    if (((idx >> cpos) & 1) && !((idx >> tpos) & 1)) {
                        int i1 = idx | tmask;
                        float tr = ar[idx]; ar[idx] = ar[i1]; ar[i1] = tr;
                        float ti = ai[idx]; ai[idx] = ai[i1]; ai[i1] = ti;
                    }
                }
            }
        }
        for (int i = 0; i < DIM; ++i) { Ur[i][col] = ar[i]; Ui[i][col] = ai[i]; }
    }
    __syncthreads();

    // ---- Phase 2: A_w[j][k], one (j,k) per thread, 4 outputs share products ----
    {
        int j = threadIdx.x >> 4, k = threadIdx.x & 15;
        float a0 = 0.f, a1 = 0.f, a2 = 0.f, a3 = 0.f;
#pragma unroll
        for (int idx = 0; idx < DIM; ++idx) {
            float rr = Ur[idx][j] * Ur[idx][k] + Ui[idx][j] * Ui[idx][k];
            a0 += (idx & 8) ? -rr : rr;
            a1 += (idx & 4) ? -rr : rr;
            a2 += (idx & 2) ? -rr : rr;
            a3 += (idx & 1) ? -rr : rr;
        }
        A[0][j][k] = a0; A[1][j][k] = a1; A[2][j][k] = a2; A[3][j][k] = a3;
    }
    __syncthreads();

    // ---- Phase 3: K transform, 324 scalars into lk (grid-stride: 324 > 256!) ----
    for (int id = threadIdx.x; id < 4 * 81; id += blockDim.x) {
        int w = id & 3, u = id >> 2;
        int e0 = u / 27, e1 = (u / 9) % 3, e2 = (u / 3) % 3, e3 = u % 3;
        int m  = ((e0 == 2) ? 8 : 0) | ((e1 == 2) ? 4 : 0) | ((e2 == 2) ? 2 : 0) | ((e3 == 2) ? 1 : 0);
        int d1 = ((e0 == 1) ? 8 : 0) | ((e1 == 1) ? 4 : 0) | ((e2 == 1) ? 2 : 0) | ((e3 == 1) ? 1 : 0);
        float acc = 0.f;
#pragma unroll
        for (int b = 0; b < DIM; ++b) {
            float sgn = (__popc(b & d1) & 1) ? -1.f : 1.f;
            acc += sgn * A[w][b][b ^ m];
        }
        ((float*)lk)[u * 4 + w] = 0.0625f * acc;
    }
    __syncthreads();

    // ---- Phase 4: per-sample contraction (2 samples/thread, coalesced) ----
    if (!valid) return;
    float ta[9], ua[9], tb[9], ub[9];
    build9(xa.x, xa.y, ta);  build9(xa.z, xa.w, ua);
    build9(xb.x, xb.y, tb);  build9(xb.z, xb.w, ub);

    float4 accA = make_float4(0.f, 0.f, 0.f, 0.f);
    float4 accB = make_float4(0.f, 0.f, 0.f, 0.f);
#pragma unroll
    for (int i = 0; i < 9; ++i) {
#pragma unroll
        for (int j = 0; j < 9; ++j) {
            float4 c = lk[i * 9 + j];   // ds_read_b128, imm offset, broadcast
            float pa = ta[i] * ua[j];
            float pb = tb[i] * ub[j];
            accA.x = fmaf(c.x, pa, accA.x);
            accA.y = fmaf(c.y, pa, accA.y);
            accA.z = fmaf(c.z, pa, accA.z);
            accA.w = fmaf(c.w, pa, accA.w);
            accB.x = fmaf(c.x, pb, accB.x);
            accB.y = fmaf(c.y, pb, accB.y);
            accB.z = fmaf(c.z, pb, accB.z);
            accB.w = fmaf(c.w, pb, accB.w);
        }
    }
    out[tid] = accA;
    out[tid + half] = accB;
}

extern "C" void kernel_launch(void* const* d_in, const int* in_sizes, int n_in,
                              void* d_out, int out_size, void* d_ws, size_t ws_size,
                              hipStream_t stream) {
    const float* x = (const float*)d_in[0];
    const float* wt = (const float*)d_in[1];
    float* out = (float*)d_out;
    (void)d_ws; (void)ws_size;

    int B = in_sizes[0] / NQ;   // 2^20 samples
    int half = B / 2;           // 2 samples per thread
    int blocks = (half + 255) / 256;   // 2048 blocks = 8/CU
    qsim_kernel<<<blocks, 256, 0, stream>>>((const float4*)x, wt, (float4*)out, half);
}